// Round 10
// baseline (611.493 us; speedup 1.0000x reference)
//
#include <hip/hip_runtime.h>
#include <hip/hip_fp16.h>

#define NN 100000
#define EE 3200000
#define BB 128
#define MM (EE + NN)            // edges incl. self-loops
#define NBK 391                 // buckets of 256 nodes: (NN+255)/256
#define CHUNK 8192
#define NCH ((MM + CHUNK - 1) / CHUNK)   // 403

// ---------------- setup kernels ----------------

__global__ void k_init(int* __restrict__ bstart, int* __restrict__ bend,
                       int* __restrict__ gcnt) {
  int i = blockIdx.x * 256 + threadIdx.x;
  if (i < BB) { bstart[i] = 0; bend[i] = 0; }
  if (i < NBK) gcnt[i] = 0;
}

// per-block LDS histogram of dst buckets -> global bucket counts (NO per-node atomics)
__global__ __launch_bounds__(256) void k_hist(const int* __restrict__ ei, int* __restrict__ gcnt) {
  __shared__ int lh[NBK];
  int t = threadIdx.x;
  for (int b = t; b < NBK; b += 256) lh[b] = 0;
  __syncthreads();
  int base = blockIdx.x * CHUNK;
  for (int i = t; i < CHUNK; i += 256) {
    int e = base + i; if (e >= MM) break;
    int d = (e < EE) ? ei[EE + e] : (e - EE);
    atomicAdd(&lh[d >> 8], 1);
  }
  __syncthreads();
  for (int b = t; b < NBK; b += 256) { int c = lh[b]; if (c) atomicAdd(&gcnt[b], c); }
}

// exclusive scan of bucket counts -> scatter cursors + immutable bucket offsets; rs[NN]=MM
__global__ void k_bscan(const int* __restrict__ gcnt, int* __restrict__ curB,
                        int* __restrict__ bktoff, int* __restrict__ rs) {
  __shared__ int sc[512];
  int t = threadIdx.x;
  int v = (t < NBK) ? gcnt[t] : 0;
  sc[t] = v; __syncthreads();
  for (int off = 1; off < 512; off <<= 1) {
    int u = (t >= off) ? sc[t - off] : 0;
    __syncthreads();
    sc[t] += u;
    __syncthreads();
  }
  int ex = sc[t] - v;                  // exclusive prefix (v=0 for t>=NBK)
  if (t < NBK) curB[t] = ex;
  if (t <= NBK) bktoff[t] = ex;        // bktoff[NBK] == MM
  if (t == 0) rs[NN] = MM;
}

// scatter edges into bucket-sorted PACKED array: (src<<8)|local_dst  (src<2^17, dl<256)
__global__ __launch_bounds__(256) void k_scatter(const int* __restrict__ ei,
                                                 int* __restrict__ curB, int* __restrict__ bkt) {
  __shared__ int lh[NBK];
  __shared__ int lbase[NBK];
  int t = threadIdx.x;
  for (int b = t; b < NBK; b += 256) lh[b] = 0;
  __syncthreads();
  int base = blockIdx.x * CHUNK;
  for (int i = t; i < CHUNK; i += 256) {
    int e = base + i; if (e >= MM) break;
    int d = (e < EE) ? ei[EE + e] : (e - EE);
    atomicAdd(&lh[d >> 8], 1);
  }
  __syncthreads();
  for (int b = t; b < NBK; b += 256) {
    int c = lh[b];
    lbase[b] = c ? atomicAdd(&curB[b], c) : 0;
    lh[b] = 0;
  }
  __syncthreads();
  for (int i = t; i < CHUNK; i += 256) {
    int e = base + i; if (e >= MM) break;
    int s, d;
    if (e < EE) { s = ei[e]; d = ei[EE + e]; } else { s = e - EE; d = s; }
    int b = d >> 8;
    int r = atomicAdd(&lh[b], 1);
    bkt[lbase[b] + r] = (s << 8) | (d & 255);
  }
}

// per-bucket: count (LDS) -> scan (LDS) -> rs/dis -> fill srcs (LDS cursors).
// CSR row order == bucket order, so rs[node] = bktoff[b] + within-bucket prefix.
__global__ __launch_bounds__(256) void k_bucket(const int* __restrict__ bkt,
                                                const int* __restrict__ bktoff,
                                                float* __restrict__ dis, int* __restrict__ rs,
                                                int* __restrict__ srcs) {
  int b = blockIdx.x, t = threadIdx.x;
  int start = bktoff[b], end = bktoff[b + 1];
  int nbase = b << 8;
  __shared__ int cnt[256];
  __shared__ int scn[256];
  __shared__ int curs[256];
  cnt[t] = 0;
  __syncthreads();
  for (int i = start + t; i < end; i += 256)
    atomicAdd(&cnt[bkt[i] & 255], 1);
  __syncthreads();
  int v = cnt[t];
  scn[t] = v; __syncthreads();
  for (int off = 1; off < 256; off <<= 1) {
    int u = (t >= off) ? scn[t - off] : 0;
    __syncthreads();
    scn[t] += u;
    __syncthreads();
  }
  int excl = scn[t] - v;
  int node = nbase + t;
  if (node < NN) {
    rs[node] = start + excl;
    dis[node] = rsqrtf((float)v);      // v >= 1 for all real nodes (self-loop)
  }
  curs[t] = start + excl;
  __syncthreads();
  for (int i = start + t; i < end; i += 256) {
    int e = bkt[i];
    int pos = atomicAdd(&curs[e & 255], 1);
    srcs[pos] = ((unsigned)e) >> 8;
  }
}

// batch is SORTED -> segment boundaries via adjacent compare; zero atomics.
__global__ void k_bounds(const int* __restrict__ batch, int* __restrict__ bstart,
                         int* __restrict__ bend) {
  int i = blockIdx.x * 256 + threadIdx.x;
  if (i >= NN) return;
  int b = batch[i];
  if (i == 0 || batch[i - 1] != b) bstart[b] = i;
  if (i == NN - 1 || batch[i + 1] != b) bend[b] = i + 1;
}

// ---------------- matmul: tp[r][c] = fp16( dis[r] * sum_k in[r][k] W[k][c] ) ----------------

template <int CIN>
__global__ __launch_bounds__(256) void k_matmul_scale(
    const float* __restrict__ in, const float* __restrict__ W,
    const float* __restrict__ dis, ushort* __restrict__ out) {
  __shared__ float Wl[CIN * 64];
  __shared__ float xr[64 * 68];
  int t = threadIdx.x;
  for (int i = t * 4; i < CIN * 64; i += 1024)
    *(float4*)&Wl[i] = *(const float4*)&W[i];

  int base = blockIdx.x * 64;
  int rows = NN - base; if (rows > 64) rows = 64;

  int cg = t & 15, rg = t >> 4;
  int c0 = cg * 4;
  float acc[4][4] = {};

  for (int kh = 0; kh < CIN; kh += 64) {
    for (int i = t * 4; i < rows * 64; i += 1024) {
      int r = i >> 6, c = i & 63;
      *(float4*)&xr[r * 68 + c] = *(const float4*)&in[(base + r) * CIN + kh + c];
    }
    __syncthreads();
#pragma unroll
    for (int kl = 0; kl < 64; kl += 4) {
      float4 xv[4], wv[4];
#pragma unroll
      for (int j = 0; j < 4; j++) xv[j] = *(float4*)&xr[(rg * 4 + j) * 68 + kl];
#pragma unroll
      for (int kk = 0; kk < 4; kk++) wv[kk] = *(float4*)&Wl[(kh + kl + kk) * 64 + c0];
#pragma unroll
      for (int kk = 0; kk < 4; kk++) {
#pragma unroll
        for (int j = 0; j < 4; j++) {
          float xs = (&xv[j].x)[kk];
          acc[j][0] += xs * wv[kk].x;
          acc[j][1] += xs * wv[kk].y;
          acc[j][2] += xs * wv[kk].z;
          acc[j][3] += xs * wv[kk].w;
        }
      }
    }
    __syncthreads();
  }

#pragma unroll
  for (int j = 0; j < 4; j++) {
    int r = base + rg * 4 + j;
    if (r < NN) {
      float dv = dis[r];
      ushort4 o;
      o.x = __half_as_ushort(__float2half_rn(acc[j][0] * dv));
      o.y = __half_as_ushort(__float2half_rn(acc[j][1] * dv));
      o.z = __half_as_ushort(__float2half_rn(acc[j][2] * dv));
      o.w = __half_as_ushort(__float2half_rn(acc[j][3] * dv));
      *(ushort4*)&out[r * 64 + c0] = o;
    }
  }
}

// ---------------- aggregation: one wave per node; pair-packed channels ----------------
// lane handles channels {2c, 2c+1} (c = lane&31) of row-half (lane>>5).
// One uint load = 2 fp16 channels; one VMEM instruction fetches TWO edge rows.
// NEW: v_pk_add_f16 accumulation (1 inst vs 2 cvt + 2 add), flushed to fp32
// every <=8 edges so fp16 partial-sum error stays bounded (~1e-3, same order
// as the fp16 quantization already validated).

__global__ __launch_bounds__(256) void k_agg(
    const ushort* __restrict__ tp, const int* __restrict__ row_start,
    const int* __restrict__ srcs, const float* __restrict__ dis,
    const float* __restrict__ bias, float* __restrict__ out) {
  int wid = (blockIdx.x * 256 + threadIdx.x) >> 6;
  int lane = threadIdx.x & 63;
  if (wid >= NN) return;
  int s = row_start[wid], e = row_start[wid + 1];
  int half = lane >> 5;
  int cp = lane & 31;                   // channel pair index
  float fx = 0.f, fy = 0.f;

  int p = s;
  for (; p + 16 <= e; p += 16) {
    int idx = srcs[p + (lane & 15)];    // one coalesced load of 16 indices
    __half2 hs = __float2half2_rn(0.f);
#pragma unroll
    for (int j = 0; j < 8; j++) {
      int r = __shfl(idx, 2 * j + half, 16);
      uint u = *(const uint*)(tp + (((size_t)r) << 6) + (cp << 1));
      hs = __hadd2(hs, *(const __half2*)&u);     // v_pk_add_f16
    }
    float2 f = __half22float2(hs);               // flush: <=8 fp16 adds per group
    fx += f.x; fy += f.y;
  }
  {
    __half2 hs = __float2half2_rn(0.f);
    for (; p + 2 <= e; p += 2) {        // pair tail (<=7 pairs -> bounded)
      int r = srcs[p + half];
      uint u = *(const uint*)(tp + (((size_t)r) << 6) + (cp << 1));
      hs = __hadd2(hs, *(const __half2*)&u);
    }
    if (p < e && half == 0) {           // last odd edge: half 0 only
      int r = srcs[p];
      uint u = *(const uint*)(tp + (((size_t)r) << 6) + (cp << 1));
      hs = __hadd2(hs, *(const __half2*)&u);
    }
    float2 f = __half22float2(hs);
    fx += f.x; fy += f.y;
  }

  fx += __shfl_xor(fx, 32);
  fy += __shfl_xor(fy, 32);

  if (half == 0) {
    float dv = dis[wid];
    float2 bv = *(const float2*)&bias[cp * 2];
    float2 o;
    o.x = fmaxf(fx * dv + bv.x, 0.f);
    o.y = fmaxf(fy * dv + bv.y, 0.f);
    *(float2*)&out[wid * 64 + cp * 2] = o;
  }
}

// ---------------- fused mean-pool + 2-layer MLP ----------------

__global__ __launch_bounds__(256) void k_pool_mlp(
    const float* __restrict__ h, const int* __restrict__ bstart, const int* __restrict__ bend,
    const float* __restrict__ Wm1, const float* __restrict__ bm1,
    const float* __restrict__ Wm2, const float* __restrict__ bm2,
    float* __restrict__ out) {
  int b = blockIdx.x;
  int t = threadIdx.x;
  int lane = t & 63, w = t >> 6;
  int s = bstart[b], e = bend[b];
  float acc = 0.f;
  for (int i = s + w; i < e; i += 4) acc += h[i * 64 + lane];
  __shared__ float sums[4][64];
  __shared__ float pooled[64];
  sums[w][lane] = acc;
  __syncthreads();
  if (t < 64) {
    float tot = sums[0][t] + sums[1][t] + sums[2][t] + sums[3][t];
    int cnt = e - s;
    pooled[t] = tot / fmaxf((float)cnt, 1.0f);
  }
  __syncthreads();
  if (t < 32) {
    float z = bm1[t];
#pragma unroll
    for (int c = 0; c < 64; c++) z += pooled[c] * Wm1[c * 32 + t];
    z = fmaxf(z, 0.f) * Wm2[t];
#pragma unroll
    for (int off = 16; off > 0; off >>= 1) z += __shfl_down(z, off, 32);
    if (t == 0) out[b] = z + bm2[0];
  }
}

// ---------------- launch ----------------

extern "C" void kernel_launch(void* const* d_in, const int* in_sizes, int n_in,
                              void* d_out, int out_size, void* d_ws, size_t ws_size,
                              hipStream_t stream) {
  const float* x   = (const float*)d_in[0];
  const int*   ei  = (const int*)d_in[1];
  const int*   bat = (const int*)d_in[2];
  const float* W0  = (const float*)d_in[3];
  const float* b0  = (const float*)d_in[4];
  const float* W1  = (const float*)d_in[5];
  const float* b1  = (const float*)d_in[6];
  const float* W2  = (const float*)d_in[7];
  const float* b2  = (const float*)d_in[8];
  const float* Wm1 = (const float*)d_in[9];
  const float* bm1 = (const float*)d_in[10];
  const float* Wm2 = (const float*)d_in[11];
  const float* bm2 = (const float*)d_in[12];
  float* out = (float*)d_out;

  char* ws = (char*)d_ws;
  size_t off = 0;
  auto alloc = [&](size_t bytes) -> void* {
    void* p = ws + off; off += (bytes + 255) & ~(size_t)255; return p;
  };
  float*  dis    = (float*) alloc((size_t)NN * 4);
  int*    rs     = (int*)   alloc((size_t)(NN + 1) * 4);
  int*    srcs   = (int*)   alloc((size_t)MM * 4);
  // region shared by bkt (packed int, 13.2 MB, CSR build only) and h (fp32, 25.6 MB, after)
  void*   regA   = alloc((size_t)MM * 8);
  ushort* tp     = (ushort*)alloc((size_t)NN * 64 * 2);   // fp16 gather table
  int*    bst    = (int*)   alloc(BB * 4);
  int*    ben    = (int*)   alloc(BB * 4);
  int*    gcnt   = (int*)   alloc(NBK * 4);
  int*    curB   = (int*)   alloc(NBK * 4);
  int*    bktoff = (int*)   alloc((NBK + 1) * 4);

  int*   bkt = (int*)regA;
  float* h   = (float*)regA;

  k_init<<<2, 256, 0, stream>>>(bst, ben, gcnt);
  k_hist<<<NCH, 256, 0, stream>>>(ei, gcnt);
  k_bscan<<<1, 512, 0, stream>>>(gcnt, curB, bktoff, rs);
  k_scatter<<<NCH, 256, 0, stream>>>(ei, curB, bkt);
  k_bucket<<<NBK, 256, 0, stream>>>(bkt, bktoff, dis, rs, srcs);
  k_bounds<<<(NN + 255) / 256, 256, 0, stream>>>(bat, bst, ben);

  const int mmgrid = (NN + 63) / 64;      // 1563

  k_matmul_scale<128><<<mmgrid, 256, 0, stream>>>(x, W0, dis, tp);
  k_agg<<<(NN + 3) / 4, 256, 0, stream>>>(tp, rs, srcs, dis, b0, h);

  k_matmul_scale<64><<<mmgrid, 256, 0, stream>>>(h, W1, dis, tp);
  k_agg<<<(NN + 3) / 4, 256, 0, stream>>>(tp, rs, srcs, dis, b1, h);

  k_matmul_scale<64><<<mmgrid, 256, 0, stream>>>(h, W2, dis, tp);
  k_agg<<<(NN + 3) / 4, 256, 0, stream>>>(tp, rs, srcs, dis, b2, h);

  k_pool_mlp<<<BB, 256, 0, stream>>>(h, bst, ben, Wm1, bm1, Wm2, bm2, out);
}

// Round 11
// 605.592 us; speedup vs baseline: 1.0097x; 1.0097x over previous
//
#include <hip/hip_runtime.h>
#include <hip/hip_fp16.h>
#include <hip/hip_fp8.h>

#define NN 100000
#define EE 3200000
#define BB 128
#define MM (EE + NN)            // edges incl. self-loops
#define NBK 391                 // buckets of 256 nodes: (NN+255)/256
#define CHUNK 8192
#define NCH ((MM + CHUNK - 1) / CHUNK)   // 403

// ---------------- setup kernels ----------------

__global__ void k_init(int* __restrict__ bstart, int* __restrict__ bend,
                       int* __restrict__ gcnt) {
  int i = blockIdx.x * 256 + threadIdx.x;
  if (i < BB) { bstart[i] = 0; bend[i] = 0; }
  if (i < NBK) gcnt[i] = 0;
}

// per-block LDS histogram of dst buckets -> global bucket counts (NO per-node atomics)
__global__ __launch_bounds__(256) void k_hist(const int* __restrict__ ei, int* __restrict__ gcnt) {
  __shared__ int lh[NBK];
  int t = threadIdx.x;
  for (int b = t; b < NBK; b += 256) lh[b] = 0;
  __syncthreads();
  int base = blockIdx.x * CHUNK;
  for (int i = t; i < CHUNK; i += 256) {
    int e = base + i; if (e >= MM) break;
    int d = (e < EE) ? ei[EE + e] : (e - EE);
    atomicAdd(&lh[d >> 8], 1);
  }
  __syncthreads();
  for (int b = t; b < NBK; b += 256) { int c = lh[b]; if (c) atomicAdd(&gcnt[b], c); }
}

// exclusive scan of bucket counts -> scatter cursors + immutable bucket offsets; rs[NN]=MM
__global__ void k_bscan(const int* __restrict__ gcnt, int* __restrict__ curB,
                        int* __restrict__ bktoff, int* __restrict__ rs) {
  __shared__ int sc[512];
  int t = threadIdx.x;
  int v = (t < NBK) ? gcnt[t] : 0;
  sc[t] = v; __syncthreads();
  for (int off = 1; off < 512; off <<= 1) {
    int u = (t >= off) ? sc[t - off] : 0;
    __syncthreads();
    sc[t] += u;
    __syncthreads();
  }
  int ex = sc[t] - v;                  // exclusive prefix (v=0 for t>=NBK)
  if (t < NBK) curB[t] = ex;
  if (t <= NBK) bktoff[t] = ex;        // bktoff[NBK] == MM
  if (t == 0) rs[NN] = MM;
}

// scatter edges into bucket-sorted PACKED array: (src<<8)|local_dst  (src<2^17, dl<256)
__global__ __launch_bounds__(256) void k_scatter(const int* __restrict__ ei,
                                                 int* __restrict__ curB, int* __restrict__ bkt) {
  __shared__ int lh[NBK];
  __shared__ int lbase[NBK];
  int t = threadIdx.x;
  for (int b = t; b < NBK; b += 256) lh[b] = 0;
  __syncthreads();
  int base = blockIdx.x * CHUNK;
  for (int i = t; i < CHUNK; i += 256) {
    int e = base + i; if (e >= MM) break;
    int d = (e < EE) ? ei[EE + e] : (e - EE);
    atomicAdd(&lh[d >> 8], 1);
  }
  __syncthreads();
  for (int b = t; b < NBK; b += 256) {
    int c = lh[b];
    lbase[b] = c ? atomicAdd(&curB[b], c) : 0;
    lh[b] = 0;
  }
  __syncthreads();
  for (int i = t; i < CHUNK; i += 256) {
    int e = base + i; if (e >= MM) break;
    int s, d;
    if (e < EE) { s = ei[e]; d = ei[EE + e]; } else { s = e - EE; d = s; }
    int b = d >> 8;
    int r = atomicAdd(&lh[b], 1);
    bkt[lbase[b] + r] = (s << 8) | (d & 255);
  }
}

// per-bucket: count (LDS) -> scan (LDS) -> rs/dis -> fill srcs (LDS cursors).
__global__ __launch_bounds__(256) void k_bucket(const int* __restrict__ bkt,
                                                const int* __restrict__ bktoff,
                                                float* __restrict__ dis, int* __restrict__ rs,
                                                int* __restrict__ srcs) {
  int b = blockIdx.x, t = threadIdx.x;
  int start = bktoff[b], end = bktoff[b + 1];
  int nbase = b << 8;
  __shared__ int cnt[256];
  __shared__ int scn[256];
  __shared__ int curs[256];
  cnt[t] = 0;
  __syncthreads();
  for (int i = start + t; i < end; i += 256)
    atomicAdd(&cnt[bkt[i] & 255], 1);
  __syncthreads();
  int v = cnt[t];
  scn[t] = v; __syncthreads();
  for (int off = 1; off < 256; off <<= 1) {
    int u = (t >= off) ? scn[t - off] : 0;
    __syncthreads();
    scn[t] += u;
    __syncthreads();
  }
  int excl = scn[t] - v;
  int node = nbase + t;
  if (node < NN) {
    rs[node] = start + excl;
    dis[node] = rsqrtf((float)v);      // v >= 1 for all real nodes (self-loop)
  }
  curs[t] = start + excl;
  __syncthreads();
  for (int i = start + t; i < end; i += 256) {
    int e = bkt[i];
    int pos = atomicAdd(&curs[e & 255], 1);
    srcs[pos] = ((unsigned)e) >> 8;
  }
}

// batch is SORTED -> segment boundaries via adjacent compare; zero atomics.
__global__ void k_bounds(const int* __restrict__ batch, int* __restrict__ bstart,
                         int* __restrict__ bend) {
  int i = blockIdx.x * 256 + threadIdx.x;
  if (i >= NN) return;
  int b = batch[i];
  if (i == 0 || batch[i - 1] != b) bstart[b] = i;
  if (i == NN - 1 || batch[i + 1] != b) bend[b] = i + 1;
}

// ---------------- matmul: tp[r][c] = fp8_e4m3( dis[r] * sum_k in[r][k] W[k][c] ) ----------------

template <int CIN>
__global__ __launch_bounds__(256) void k_matmul_scale(
    const float* __restrict__ in, const float* __restrict__ W,
    const float* __restrict__ dis, unsigned char* __restrict__ out) {
  __shared__ float Wl[CIN * 64];
  __shared__ float xr[64 * 68];
  int t = threadIdx.x;
  for (int i = t * 4; i < CIN * 64; i += 1024)
    *(float4*)&Wl[i] = *(const float4*)&W[i];

  int base = blockIdx.x * 64;
  int rows = NN - base; if (rows > 64) rows = 64;

  int cg = t & 15, rg = t >> 4;
  int c0 = cg * 4;
  float acc[4][4] = {};

  for (int kh = 0; kh < CIN; kh += 64) {
    for (int i = t * 4; i < rows * 64; i += 1024) {
      int r = i >> 6, c = i & 63;
      *(float4*)&xr[r * 68 + c] = *(const float4*)&in[(base + r) * CIN + kh + c];
    }
    __syncthreads();
#pragma unroll
    for (int kl = 0; kl < 64; kl += 4) {
      float4 xv[4], wv[4];
#pragma unroll
      for (int j = 0; j < 4; j++) xv[j] = *(float4*)&xr[(rg * 4 + j) * 68 + kl];
#pragma unroll
      for (int kk = 0; kk < 4; kk++) wv[kk] = *(float4*)&Wl[(kh + kl + kk) * 64 + c0];
#pragma unroll
      for (int kk = 0; kk < 4; kk++) {
#pragma unroll
        for (int j = 0; j < 4; j++) {
          float xs = (&xv[j].x)[kk];
          acc[j][0] += xs * wv[kk].x;
          acc[j][1] += xs * wv[kk].y;
          acc[j][2] += xs * wv[kk].z;
          acc[j][3] += xs * wv[kk].w;
        }
      }
    }
    __syncthreads();
  }

#pragma unroll
  for (int j = 0; j < 4; j++) {
    int r = base + rg * 4 + j;
    if (r < NN) {
      float dv = dis[r];
      __hip_fp8x2_e4m3 plo(make_float2(acc[j][0] * dv, acc[j][1] * dv));
      __hip_fp8x2_e4m3 phi(make_float2(acc[j][2] * dv, acc[j][3] * dv));
      unsigned int u = (unsigned int)plo.__x | ((unsigned int)phi.__x << 16);
      *(unsigned int*)&out[(size_t)r * 64 + c0] = u;
    }
  }
}

// ---------------- aggregation: one wave per node; fp8 e4m3 gather table ----------------
// lane handles channels {2c, 2c+1} (c = lane&31) of row-half (lane>>5).
// One ushort load = 2 fp8 channels; one VMEM instruction fetches TWO edge rows
// (row segment = 64 B per 32 lanes). Cross-half combine via shfl_xor(32).
// fp8 -> float2 via packed cvt; fp32 accumulation throughout.

__global__ __launch_bounds__(256) void k_agg(
    const unsigned char* __restrict__ tp, const int* __restrict__ row_start,
    const int* __restrict__ srcs, const float* __restrict__ dis,
    const float* __restrict__ bias, float* __restrict__ out) {
  int wid = (blockIdx.x * 256 + threadIdx.x) >> 6;
  int lane = threadIdx.x & 63;
  if (wid >= NN) return;
  int s = row_start[wid], e = row_start[wid + 1];
  int half = lane >> 5;
  int cp = lane & 31;                   // channel pair index
  float fx0 = 0.f, fy0 = 0.f, fx1 = 0.f, fy1 = 0.f;

  int p = s;
  for (; p + 16 <= e; p += 16) {
    int idx = srcs[p + (lane & 15)];    // one coalesced load of 16 indices
#pragma unroll
    for (int j = 0; j < 8; j++) {
      int r = __shfl(idx, 2 * j + half, 16);
      ushort us = *(const ushort*)(tp + (((size_t)r) << 6) + (cp << 1));
      __hip_fp8x2_e4m3 pk; pk.__x = us;
      float2 f = (float2)pk;
      if (j & 1) { fx1 += f.x; fy1 += f.y; } else { fx0 += f.x; fy0 += f.y; }
    }
  }
  for (; p + 2 <= e; p += 2) {          // pair tail
    int r = srcs[p + half];
    ushort us = *(const ushort*)(tp + (((size_t)r) << 6) + (cp << 1));
    __hip_fp8x2_e4m3 pk; pk.__x = us;
    float2 f = (float2)pk;
    fx0 += f.x; fy0 += f.y;
  }
  if (p < e && half == 0) {             // last odd edge: half 0 only
    int r = srcs[p];
    ushort us = *(const ushort*)(tp + (((size_t)r) << 6) + (cp << 1));
    __hip_fp8x2_e4m3 pk; pk.__x = us;
    float2 f = (float2)pk;
    fx0 += f.x; fy0 += f.y;
  }

  float fx = fx0 + fx1, fy = fy0 + fy1;
  fx += __shfl_xor(fx, 32);
  fy += __shfl_xor(fy, 32);

  if (half == 0) {
    float dv = dis[wid];
    float2 bv = *(const float2*)&bias[cp * 2];
    float2 o;
    o.x = fmaxf(fx * dv + bv.x, 0.f);
    o.y = fmaxf(fy * dv + bv.y, 0.f);
    *(float2*)&out[wid * 64 + cp * 2] = o;
  }
}

// ---------------- fused mean-pool + 2-layer MLP ----------------

__global__ __launch_bounds__(256) void k_pool_mlp(
    const float* __restrict__ h, const int* __restrict__ bstart, const int* __restrict__ bend,
    const float* __restrict__ Wm1, const float* __restrict__ bm1,
    const float* __restrict__ Wm2, const float* __restrict__ bm2,
    float* __restrict__ out) {
  int b = blockIdx.x;
  int t = threadIdx.x;
  int lane = t & 63, w = t >> 6;
  int s = bstart[b], e = bend[b];
  float acc = 0.f;
  for (int i = s + w; i < e; i += 4) acc += h[i * 64 + lane];
  __shared__ float sums[4][64];
  __shared__ float pooled[64];
  sums[w][lane] = acc;
  __syncthreads();
  if (t < 64) {
    float tot = sums[0][t] + sums[1][t] + sums[2][t] + sums[3][t];
    int cnt = e - s;
    pooled[t] = tot / fmaxf((float)cnt, 1.0f);
  }
  __syncthreads();
  if (t < 32) {
    float z = bm1[t];
#pragma unroll
    for (int c = 0; c < 64; c++) z += pooled[c] * Wm1[c * 32 + t];
    z = fmaxf(z, 0.f) * Wm2[t];
#pragma unroll
    for (int off = 16; off > 0; off >>= 1) z += __shfl_down(z, off, 32);
    if (t == 0) out[b] = z + bm2[0];
  }
}

// ---------------- launch ----------------

extern "C" void kernel_launch(void* const* d_in, const int* in_sizes, int n_in,
                              void* d_out, int out_size, void* d_ws, size_t ws_size,
                              hipStream_t stream) {
  const float* x   = (const float*)d_in[0];
  const int*   ei  = (const int*)d_in[1];
  const int*   bat = (const int*)d_in[2];
  const float* W0  = (const float*)d_in[3];
  const float* b0  = (const float*)d_in[4];
  const float* W1  = (const float*)d_in[5];
  const float* b1  = (const float*)d_in[6];
  const float* W2  = (const float*)d_in[7];
  const float* b2  = (const float*)d_in[8];
  const float* Wm1 = (const float*)d_in[9];
  const float* bm1 = (const float*)d_in[10];
  const float* Wm2 = (const float*)d_in[11];
  const float* bm2 = (const float*)d_in[12];
  float* out = (float*)d_out;

  char* ws = (char*)d_ws;
  size_t off = 0;
  auto alloc = [&](size_t bytes) -> void* {
    void* p = ws + off; off += (bytes + 255) & ~(size_t)255; return p;
  };
  float*  dis    = (float*) alloc((size_t)NN * 4);
  int*    rs     = (int*)   alloc((size_t)(NN + 1) * 4);
  int*    srcs   = (int*)   alloc((size_t)MM * 4);
  // region shared by bkt (packed int, 13.2 MB, CSR build only) and h (fp32, 25.6 MB, after)
  void*   regA   = alloc((size_t)MM * 8);
  unsigned char* tp = (unsigned char*)alloc((size_t)NN * 64);   // fp8 e4m3 gather table
  int*    bst    = (int*)   alloc(BB * 4);
  int*    ben    = (int*)   alloc(BB * 4);
  int*    gcnt   = (int*)   alloc(NBK * 4);
  int*    curB   = (int*)   alloc(NBK * 4);
  int*    bktoff = (int*)   alloc((NBK + 1) * 4);

  int*   bkt = (int*)regA;
  float* h   = (float*)regA;

  k_init<<<2, 256, 0, stream>>>(bst, ben, gcnt);
  k_hist<<<NCH, 256, 0, stream>>>(ei, gcnt);
  k_bscan<<<1, 512, 0, stream>>>(gcnt, curB, bktoff, rs);
  k_scatter<<<NCH, 256, 0, stream>>>(ei, curB, bkt);
  k_bucket<<<NBK, 256, 0, stream>>>(bkt, bktoff, dis, rs, srcs);
  k_bounds<<<(NN + 255) / 256, 256, 0, stream>>>(bat, bst, ben);

  const int mmgrid = (NN + 63) / 64;      // 1563

  k_matmul_scale<128><<<mmgrid, 256, 0, stream>>>(x, W0, dis, tp);
  k_agg<<<(NN + 3) / 4, 256, 0, stream>>>(tp, rs, srcs, dis, b0, h);

  k_matmul_scale<64><<<mmgrid, 256, 0, stream>>>(h, W1, dis, tp);
  k_agg<<<(NN + 3) / 4, 256, 0, stream>>>(tp, rs, srcs, dis, b1, h);

  k_matmul_scale<64><<<mmgrid, 256, 0, stream>>>(h, W2, dis, tp);
  k_agg<<<(NN + 3) / 4, 256, 0, stream>>>(tp, rs, srcs, dis, b2, h);

  k_pool_mlp<<<BB, 256, 0, stream>>>(h, bst, ben, Wm1, bm1, Wm2, bm2, out);
}